// Round 10
// baseline (445.530 us; speedup 1.0000x reference)
//
#include <hip/hip_runtime.h>
#include <cstdint>
#include <cstddef>

#define S_LEN 4096
#define DVEC  1024
#define DH    256

typedef __attribute__((ext_vector_type(8))) short short8;
typedef __attribute__((ext_vector_type(4))) float f32x4;
typedef __attribute__((ext_vector_type(4))) unsigned short ushort4v;
typedef unsigned long long ull;

__device__ __forceinline__ unsigned short f2bf(float f) {
  unsigned u = __builtin_bit_cast(unsigned, f);
  u += 0x7FFFu + ((u >> 16) & 1u);          // round-to-nearest-even
  return (unsigned short)(u >> 16);
}

__device__ __forceinline__ void gl2lds16(const void* g, void* lds) {
  __builtin_amdgcn_global_load_lds(
      (const __attribute__((address_space(1))) unsigned int*)g,
      (__attribute__((address_space(3))) unsigned int*)lds, 16, 0, 0);
}

// ---------------------------------------------------------------------------
// Kernel 0: mask int32[4][4096][4096] -> bits uint64[4][4096][64].
// (verbatim — correctness-verified r6/r9)
// ---------------------------------------------------------------------------
__global__ void mcomp_kernel(const int* __restrict__ mask,
                             ull* __restrict__ mbits) {
  const int lane = threadIdx.x & 63;
  const int wid  = (int)((blockIdx.x * blockDim.x + threadIdx.x) >> 6); // 0..4095
  const size_t base = (size_t)wid * 256;   // 256 words per wave
#pragma unroll 4
  for (int i = 0; i < 64; ++i) {
    size_t w0 = base + (size_t)i * 4;
    int v0 = mask[(w0 + 0) * 64 + lane];
    int v1 = mask[(w0 + 1) * 64 + lane];
    int v2 = mask[(w0 + 2) * 64 + lane];
    int v3 = mask[(w0 + 3) * 64 + lane];
    ull b0 = __ballot(v0 != 0);
    ull b1 = __ballot(v1 != 0);
    ull b2 = __ballot(v2 != 0);
    ull b3 = __ballot(v3 != 0);
    if (lane == 0) {
      mbits[w0 + 0] = b0;
      mbits[w0 + 1] = b1;
      mbits[w0 + 2] = b2;
      mbits[w0 + 3] = b3;
    }
  }
}

// ---------------------------------------------------------------------------
// Kernel 1: weights f32 -> bf16 (wq pre-scaled by 1/sqrt(DH)=1/16).
// ---------------------------------------------------------------------------
__global__ void wcvt_kernel(const float* __restrict__ wq,
                            const float* __restrict__ wk,
                            const float* __restrict__ wv,
                            unsigned short* __restrict__ wbf) {
  int t   = blockIdx.x * 256 + threadIdx.x;
  int idx = t * 4;
  int m   = idx >> 18;
  int off = idx & 262143;
  const float* src = (m == 0) ? wq : (m == 1) ? wk : wv;
  float scale = (m == 0) ? 0.0625f : 1.0f;
  f32x4 v = *(const f32x4*)(src + off);
  ushort4v o;
  o.x = f2bf(v.x * scale);
  o.y = f2bf(v.y * scale);
  o.z = f2bf(v.z * scale);
  o.w = f2bf(v.w * scale);
  *(ushort4v*)(wbf + idx) = o;
}

// ---------------------------------------------------------------------------
// Kernel 2: projection GEMM (unchanged). C = x * W^T + b -> bf16; z==2 -> V^T.
// ---------------------------------------------------------------------------
__global__ void proj_kernel(const float* __restrict__ xq,
                            const float* __restrict__ xk,
                            const float* __restrict__ xv,
                            const unsigned short* __restrict__ wbf,
                            const float* __restrict__ bq,
                            const float* __restrict__ bk,
                            const float* __restrict__ bv,
                            unsigned short* __restrict__ qbf,
                            unsigned short* __restrict__ kbf,
                            unsigned short* __restrict__ vtbf) {
  const int tid  = threadIdx.x;
  const int lane = tid & 63;
  const int w    = tid >> 6;
  const int z    = blockIdx.z;
  const int m0   = blockIdx.x * 64;

  const float* x = (z == 0) ? xq : (z == 1) ? xk : xv;
  const unsigned short* wz = wbf + (size_t)z * (DH * DVEC);
  const float* bias = (z == 0) ? bq : (z == 1) ? bk : bv;
  const float bscale = (z == 0) ? 0.0625f : 1.0f;

  __shared__ float At[2][64 * 32];

  f32x4 zero = {0.f, 0.f, 0.f, 0.f};
  f32x4 acc[4][4];
#pragma unroll
  for (int i = 0; i < 4; ++i)
#pragma unroll
    for (int j = 0; j < 4; ++j) acc[i][j] = zero;

  auto stage = [&](int kt, int buf) {
    char* dstb = (char*)&At[buf][0] + w * 2048;
#pragma unroll
    for (int i = 0; i < 2; ++i) {
      int lin  = w * 2048 + i * 1024 + lane * 16;
      int row  = lin >> 7;
      int scol = (lin ^ ((row & 7) << 4)) & 127;
      gl2lds16((const char*)x + ((size_t)(m0 + row) * DVEC + kt * 32) * 4 + scol,
               dstb + i * 1024);
    }
  };

  stage(0, 0);
  __syncthreads();

  for (int kt = 0; kt < 32; ++kt) {
    const int buf = kt & 1;
    if (kt + 1 < 32) stage(kt + 1, buf ^ 1);

    short8 bfr[4];
#pragma unroll
    for (int cf = 0; cf < 4; ++cf) {
      int h = w * 64 + cf * 16 + (lane & 15);
      int d = kt * 32 + (lane >> 4) * 8;
      bfr[cf] = *(const short8*)(wz + (size_t)h * DVEC + d);
    }
    const char* ab = (const char*)&At[buf][0];
#pragma unroll
    for (int rf = 0; rf < 4; ++rf) {
      int row = rf * 16 + (lane & 15);
      int c0  = row * 128 + (lane >> 4) * 32;
      int sw  = (row & 7) << 4;
      f32x4 v0 = *(const f32x4*)(ab + (c0 ^ sw));
      f32x4 v1 = *(const f32x4*)(ab + ((c0 + 16) ^ sw));
      short8 af;
      af[0] = (short)f2bf(v0.x); af[1] = (short)f2bf(v0.y);
      af[2] = (short)f2bf(v0.z); af[3] = (short)f2bf(v0.w);
      af[4] = (short)f2bf(v1.x); af[5] = (short)f2bf(v1.y);
      af[6] = (short)f2bf(v1.z); af[7] = (short)f2bf(v1.w);
#pragma unroll
      for (int cf = 0; cf < 4; ++cf)
        acc[rf][cf] = __builtin_amdgcn_mfma_f32_16x16x32_bf16(af, bfr[cf], acc[rf][cf], 0, 0, 0);
    }
    __syncthreads();
  }

  float bvv[4];
#pragma unroll
  for (int cf = 0; cf < 4; ++cf)
    bvv[cf] = bias[w * 64 + cf * 16 + (lane & 15)] * bscale;

  if (z < 2) {
    unsigned short* o = (z == 0) ? qbf : kbf;
#pragma unroll
    for (int rf = 0; rf < 4; ++rf)
#pragma unroll
      for (int cf = 0; cf < 4; ++cf)
#pragma unroll
        for (int r = 0; r < 4; ++r) {
          int m = m0 + rf * 16 + (lane >> 4) * 4 + r;
          int h = w * 64 + cf * 16 + (lane & 15);
          o[(size_t)m * DH + h] = f2bf(acc[rf][cf][r] + bvv[cf]);
        }
  } else {
    int bb = m0 >> 12;
    int sl = m0 & 4095;
#pragma unroll
    for (int rf = 0; rf < 4; ++rf)
#pragma unroll
      for (int cf = 0; cf < 4; ++cf) {
        int s = sl + rf * 16 + (lane >> 4) * 4;
        int h = w * 64 + cf * 16 + (lane & 15);
        ushort4v o;
        o.x = f2bf(acc[rf][cf][0] + bvv[cf]);
        o.y = f2bf(acc[rf][cf][1] + bvv[cf]);
        o.z = f2bf(acc[rf][cf][2] + bvv[cf]);
        o.w = f2bf(acc[rf][cf][3] + bvv[cf]);
        *(ushort4v*)(vtbf + ((size_t)(bb * DH + h)) * S_LEN + s) = o;
      }
  }
}

// ---------------------------------------------------------------------------
// Kernel 3: fused masked attention — r9 roles/P-layout/epilogue VERBATIM, one
// structural change: NO K/V LDS staging. K and V MFMA fragments are read
// directly from global (L2/L3-resident; r5-proven access pattern). Only P
// lives in LDS, double-buffered -> ONE barrier per tile.
// Per tile t (per wave): V(t)->vreg (issued first), mask(t+1)->regs,
// K(t)-frag loads + QK MFMA, softmax (no max; exp(0)=1 = ref fill-0),
// P->LDS[t&1], barrier, PV(t) from P[t&1]+vreg.
// Buffer safety: P[t&1] reused at t+2; every wave passes t+1's barrier only
// after completing t's PV (program order) -> no clobber. LDS = 17.4 KB.
// ---------------------------------------------------------------------------
__global__ void __launch_bounds__(512, 2)
attn_kernel(const unsigned short* __restrict__ qbf,
            const unsigned short* __restrict__ kbf,
            const unsigned short* __restrict__ vtbf,
            const ull* __restrict__ mbits,
            float* __restrict__ out) {
  const int tid  = threadIdx.x;
  const int lane = tid & 63;
  const int w    = tid >> 6;          // 0..7
  const int j    = lane & 15;
  const int g    = lane >> 4;

  const int kvs = w & 3;              // QK role
  const int qh  = w >> 2;
  const int qs  = w >> 2;             // PV role
  const int hs  = w & 3;

  // XCD-aware decode (blocks on one XCD share a batch -> K/V/mask L2-warm)
  const int bx = blockIdx.x;
  const int x  = bx & 7;
  const int b  = x >> 1;
  const int qt = (bx >> 3) * 2 + (x & 1);
  const int m0 = qt * 64;

  __shared__ char sbuf[17408];
  // P: buf*8192 [0,16384) ; l: 16384 [64][4] f32
  float* lbuf = (float*)(sbuf + 16384);

  // ---- Q fragments: rows qh*32 + qf*16 + j, k-chunks kc (h = kc*32 + g*8)
  short8 qreg[2][8];
#pragma unroll
  for (int qf = 0; qf < 2; ++qf) {
    const unsigned short* qrow =
        qbf + ((size_t)(b * S_LEN + m0 + qh * 32 + qf * 16 + j)) * DH + g * 8;
#pragma unroll
    for (int kc = 0; kc < 8; ++kc) qreg[qf][kc] = *(const short8*)(qrow + kc * 32);
  }

  f32x4 zero = {0.f, 0.f, 0.f, 0.f};
  f32x4 acc[2][4];
#pragma unroll
  for (int a = 0; a < 2; ++a)
#pragma unroll
    for (int hf = 0; hf < 4; ++hf) acc[a][hf] = zero;
  float lrow[2][4] = {{0.f, 0.f, 0.f, 0.f}, {0.f, 0.f, 0.f, 0.f}};
  short8 vreg[4][2];

  // mask bits: word (b*4096 + q)*64 + t with q = m0 + qh*32 + g*4 + qf*16 + r
  const ull* mwb = mbits + ((size_t)(b * S_LEN + m0 + qh * 32 + g * 4)) * 64;
  const int mbit = kvs * 16 + j;
  int mcur[8], mnext[8];

  // K-frag direct base (QK role): row = b*S + t*64 + kvs*16 + j, 512B rows
  const char* kbase = (const char*)kbf +
      ((size_t)(b * S_LEN + kvs * 16 + j)) * 512 + g * 16;
  // V-frag direct base (PV role): row = b*DH + hs*64 + hf*16 + j, S_LEN cols
  const unsigned short* vbase =
      vtbf + ((size_t)(b * DH + hs * 64 + j)) * S_LEN + g * 8;

  // P write base (r9-verbatim layout, region base 0)
  const int pwbase = (kvs >> 1) * 1024 + ((kvs & 1) * 2 + (j >> 3)) * 256 + (j & 7) * 2;

#pragma unroll
  for (int qf = 0; qf < 2; ++qf)
#pragma unroll
    for (int r = 0; r < 4; ++r)
      mcur[qf * 4 + r] = (int)((mwb[(qf * 16 + r) * 64] >> mbit) & 1ull);

  const int NT = S_LEN / 64;   // 64
  for (int t = 0; t < NT; ++t) {
    const int pbuf = (t & 1) * 8192;

    // ---- V(t) -> regs first (oldest in FIFO; consumed after the barrier)
    {
      const unsigned short* vt = vbase + t * 64;
#pragma unroll
      for (int hf = 0; hf < 4; ++hf)
#pragma unroll
        for (int kvc = 0; kvc < 2; ++kvc)
          vreg[hf][kvc] = *(const short8*)(vt + (size_t)(hf * 16) * S_LEN + kvc * 32);
    }

    // ---- next-tile mask bits
    if (t + 1 < NT) {
#pragma unroll
      for (int qf = 0; qf < 2; ++qf)
#pragma unroll
        for (int r = 0; r < 4; ++r)
          mnext[qf * 4 + r] = (int)((mwb[(qf * 16 + r) * 64 + t + 1] >> mbit) & 1ull);
    }

    // ---- QK(t): K fragments direct from global, 4 interleaved MFMA chains
    const char* kt = kbase + (size_t)t * 64 * 512;
    f32x4 s0[2], s1[2];
    s0[0] = zero; s0[1] = zero; s1[0] = zero; s1[1] = zero;
    __builtin_amdgcn_s_setprio(1);
#pragma unroll
    for (int kc = 0; kc < 8; kc += 2) {
      short8 k0 = *(const short8*)(kt + kc * 64);
      short8 k1 = *(const short8*)(kt + (kc + 1) * 64);
      s0[0] = __builtin_amdgcn_mfma_f32_16x16x32_bf16(qreg[0][kc], k0, s0[0], 0, 0, 0);
      s0[1] = __builtin_amdgcn_mfma_f32_16x16x32_bf16(qreg[1][kc], k0, s0[1], 0, 0, 0);
      s1[0] = __builtin_amdgcn_mfma_f32_16x16x32_bf16(qreg[0][kc + 1], k1, s1[0], 0, 0, 0);
      s1[1] = __builtin_amdgcn_mfma_f32_16x16x32_bf16(qreg[1][kc + 1], k1, s1[1], 0, 0, 0);
    }
    __builtin_amdgcn_s_setprio(0);

    // ---- softmax (no max): p = maskbit ? exp(s) : 1 ; write P (bf16)
#pragma unroll
    for (int qf = 0; qf < 2; ++qf) {
      int cb = pbuf + pwbase + (qh * 2 + qf) * 2048;
#pragma unroll
      for (int r = 0; r < 4; ++r) {
        float sv = s0[qf][r] + s1[qf][r];
        sv = mcur[qf * 4 + r] ? sv : 0.0f;
        float e = __expf(sv);
        lrow[qf][r] += e;
        *(unsigned short*)(sbuf + cb + (r * 4 + g) * 16) = f2bf(e);
      }
    }

    __syncthreads();                   // single barrier: P[t&1] ready

    // ---- PV(t): P from LDS (r9 layout), V from regs
    short8 pf[2][2];
#pragma unroll
    for (int qf2 = 0; qf2 < 2; ++qf2)
#pragma unroll
      for (int kc2 = 0; kc2 < 2; ++kc2)
        pf[qf2][kc2] = *(const short8*)(sbuf + pbuf + ((qs * 2 + qf2) * 2 + kc2) * 1024 + lane * 16);
    __builtin_amdgcn_s_setprio(1);
#pragma unroll
    for (int hf = 0; hf < 4; ++hf) {
      acc[0][hf] = __builtin_amdgcn_mfma_f32_16x16x32_bf16(pf[0][0], vreg[hf][0], acc[0][hf], 0, 0, 0);
      acc[1][hf] = __builtin_amdgcn_mfma_f32_16x16x32_bf16(pf[1][0], vreg[hf][0], acc[1][hf], 0, 0, 0);
      acc[0][hf] = __builtin_amdgcn_mfma_f32_16x16x32_bf16(pf[0][1], vreg[hf][1], acc[0][hf], 0, 0, 0);
      acc[1][hf] = __builtin_amdgcn_mfma_f32_16x16x32_bf16(pf[1][1], vreg[hf][1], acc[1][hf], 0, 0, 0);
    }
    __builtin_amdgcn_s_setprio(0);

#pragma unroll
    for (int i = 0; i < 8; ++i) mcur[i] = mnext[i];
  }

  // ---- epilogue (r9-verbatim): reduce l over 16 j-lanes, exchange slices
#pragma unroll
  for (int qf = 0; qf < 2; ++qf)
#pragma unroll
    for (int r = 0; r < 4; ++r) {
#pragma unroll
      for (int off = 1; off < 16; off <<= 1)
        lrow[qf][r] += __shfl_xor(lrow[qf][r], off, 64);
    }
  if (j == 0) {
#pragma unroll
    for (int qf = 0; qf < 2; ++qf)
#pragma unroll
      for (int r = 0; r < 4; ++r)
        lbuf[(qh * 32 + qf * 16 + g * 4 + r) * 4 + kvs] = lrow[qf][r];
  }
  __syncthreads();

#pragma unroll
  for (int qf2 = 0; qf2 < 2; ++qf2)
#pragma unroll
    for (int rr = 0; rr < 4; ++rr) {
      int qb = qs * 32 + qf2 * 16 + rr * 4 + g;   // physical q (fields swapped back)
      f32x4 lv = *(const f32x4*)&lbuf[qb * 4];
      float linv = 1.0f / (lv[0] + lv[1] + lv[2] + lv[3]);
      float* orow = out + ((size_t)(b * S_LEN + m0 + qb)) * DH + hs * 64 + j;
#pragma unroll
      for (int hf = 0; hf < 4; ++hf)
        orow[hf * 16] = acc[qf2][hf][rr] * linv;
    }
}

// ---------------------------------------------------------------------------
extern "C" void kernel_launch(void* const* d_in, const int* in_sizes, int n_in,
                              void* d_out, int out_size, void* d_ws, size_t ws_size,
                              hipStream_t stream) {
  const float* xq = (const float*)d_in[0];
  const float* xk = (const float*)d_in[1];
  const float* xv = (const float*)d_in[2];
  const int* mask = (const int*)d_in[3];
  const float* wq = (const float*)d_in[4];
  const float* bq = (const float*)d_in[5];
  const float* wk = (const float*)d_in[6];
  const float* bk = (const float*)d_in[7];
  const float* wv = (const float*)d_in[8];
  const float* bv = (const float*)d_in[9];
  float* out = (float*)d_out;

  char* ws = (char*)d_ws;
  unsigned short* wbf  = (unsigned short*)(ws);                    // 1.5 MB
  unsigned short* qbf  = (unsigned short*)(ws + (2ull  << 20));    // 8 MB
  unsigned short* kbf  = (unsigned short*)(ws + (10ull << 20));    // 8 MB
  unsigned short* vtbf = (unsigned short*)(ws + (18ull << 20));    // 8 MB
  ull*            mbit = (ull*)           (ws + (26ull << 20));    // 8 MB

  hipLaunchKernelGGL(mcomp_kernel, dim3(1024), dim3(256), 0, stream, mask, mbit);
  hipLaunchKernelGGL(wcvt_kernel, dim3(768), dim3(256), 0, stream, wq, wk, wv, wbf);
  hipLaunchKernelGGL(proj_kernel, dim3(256, 1, 3), dim3(256), 0, stream,
                     xq, xk, xv, wbf, bq, bk, bv, qbf, kbf, vtbf);
  hipLaunchKernelGGL(attn_kernel, dim3(256), dim3(512), 0, stream,
                     qbf, kbf, vtbf, mbit, out);
}

// Round 11
// 380.918 us; speedup vs baseline: 1.1696x; 1.1696x over previous
//
#include <hip/hip_runtime.h>
#include <cstdint>
#include <cstddef>

#define S_LEN 4096
#define DVEC  1024
#define DH    256

typedef __attribute__((ext_vector_type(8))) short short8;
typedef __attribute__((ext_vector_type(4))) float f32x4;
typedef __attribute__((ext_vector_type(4))) unsigned short ushort4v;
typedef unsigned long long ull;

__device__ __forceinline__ unsigned short f2bf(float f) {
  unsigned u = __builtin_bit_cast(unsigned, f);
  u += 0x7FFFu + ((u >> 16) & 1u);          // round-to-nearest-even
  return (unsigned short)(u >> 16);
}

__device__ __forceinline__ void gl2lds16(const void* g, void* lds) {
  __builtin_amdgcn_global_load_lds(
      (const __attribute__((address_space(1))) unsigned int*)g,
      (__attribute__((address_space(3))) unsigned int*)lds, 16, 0, 0);
}

// ---------------------------------------------------------------------------
// Kernel 0: mask int32[4][4096][4096] -> bits uint64[4][4096][64].
// (verbatim — correctness-verified r6/r9)
// ---------------------------------------------------------------------------
__global__ void mcomp_kernel(const int* __restrict__ mask,
                             ull* __restrict__ mbits) {
  const int lane = threadIdx.x & 63;
  const int wid  = (int)((blockIdx.x * blockDim.x + threadIdx.x) >> 6); // 0..4095
  const size_t base = (size_t)wid * 256;   // 256 words per wave
#pragma unroll 4
  for (int i = 0; i < 64; ++i) {
    size_t w0 = base + (size_t)i * 4;
    int v0 = mask[(w0 + 0) * 64 + lane];
    int v1 = mask[(w0 + 1) * 64 + lane];
    int v2 = mask[(w0 + 2) * 64 + lane];
    int v3 = mask[(w0 + 3) * 64 + lane];
    ull b0 = __ballot(v0 != 0);
    ull b1 = __ballot(v1 != 0);
    ull b2 = __ballot(v2 != 0);
    ull b3 = __ballot(v3 != 0);
    if (lane == 0) {
      mbits[w0 + 0] = b0;
      mbits[w0 + 1] = b1;
      mbits[w0 + 2] = b2;
      mbits[w0 + 3] = b3;
    }
  }
}

// ---------------------------------------------------------------------------
// Kernel 1: weights f32 -> bf16 (wq pre-scaled by 1/sqrt(DH)=1/16).
// ---------------------------------------------------------------------------
__global__ void wcvt_kernel(const float* __restrict__ wq,
                            const float* __restrict__ wk,
                            const float* __restrict__ wv,
                            unsigned short* __restrict__ wbf) {
  int t   = blockIdx.x * 256 + threadIdx.x;
  int idx = t * 4;
  int m   = idx >> 18;
  int off = idx & 262143;
  const float* src = (m == 0) ? wq : (m == 1) ? wk : wv;
  float scale = (m == 0) ? 0.0625f : 1.0f;
  f32x4 v = *(const f32x4*)(src + off);
  ushort4v o;
  o.x = f2bf(v.x * scale);
  o.y = f2bf(v.y * scale);
  o.z = f2bf(v.z * scale);
  o.w = f2bf(v.w * scale);
  *(ushort4v*)(wbf + idx) = o;
}

// ---------------------------------------------------------------------------
// Kernel 2: projection GEMM (unchanged). C = x * W^T + b -> bf16; z==2 -> V^T.
// ---------------------------------------------------------------------------
__global__ void proj_kernel(const float* __restrict__ xq,
                            const float* __restrict__ xk,
                            const float* __restrict__ xv,
                            const unsigned short* __restrict__ wbf,
                            const float* __restrict__ bq,
                            const float* __restrict__ bk,
                            const float* __restrict__ bv,
                            unsigned short* __restrict__ qbf,
                            unsigned short* __restrict__ kbf,
                            unsigned short* __restrict__ vtbf) {
  const int tid  = threadIdx.x;
  const int lane = tid & 63;
  const int w    = tid >> 6;
  const int z    = blockIdx.z;
  const int m0   = blockIdx.x * 64;

  const float* x = (z == 0) ? xq : (z == 1) ? xk : xv;
  const unsigned short* wz = wbf + (size_t)z * (DH * DVEC);
  const float* bias = (z == 0) ? bq : (z == 1) ? bk : bv;
  const float bscale = (z == 0) ? 0.0625f : 1.0f;

  __shared__ float At[2][64 * 32];

  f32x4 zero = {0.f, 0.f, 0.f, 0.f};
  f32x4 acc[4][4];
#pragma unroll
  for (int i = 0; i < 4; ++i)
#pragma unroll
    for (int j = 0; j < 4; ++j) acc[i][j] = zero;

  auto stage = [&](int kt, int buf) {
    char* dstb = (char*)&At[buf][0] + w * 2048;
#pragma unroll
    for (int i = 0; i < 2; ++i) {
      int lin  = w * 2048 + i * 1024 + lane * 16;
      int row  = lin >> 7;
      int scol = (lin ^ ((row & 7) << 4)) & 127;
      gl2lds16((const char*)x + ((size_t)(m0 + row) * DVEC + kt * 32) * 4 + scol,
               dstb + i * 1024);
    }
  };

  stage(0, 0);
  __syncthreads();

  for (int kt = 0; kt < 32; ++kt) {
    const int buf = kt & 1;
    if (kt + 1 < 32) stage(kt + 1, buf ^ 1);

    short8 bfr[4];
#pragma unroll
    for (int cf = 0; cf < 4; ++cf) {
      int h = w * 64 + cf * 16 + (lane & 15);
      int d = kt * 32 + (lane >> 4) * 8;
      bfr[cf] = *(const short8*)(wz + (size_t)h * DVEC + d);
    }
    const char* ab = (const char*)&At[buf][0];
#pragma unroll
    for (int rf = 0; rf < 4; ++rf) {
      int row = rf * 16 + (lane & 15);
      int c0  = row * 128 + (lane >> 4) * 32;
      int sw  = (row & 7) << 4;
      f32x4 v0 = *(const f32x4*)(ab + (c0 ^ sw));
      f32x4 v1 = *(const f32x4*)(ab + ((c0 + 16) ^ sw));
      short8 af;
      af[0] = (short)f2bf(v0.x); af[1] = (short)f2bf(v0.y);
      af[2] = (short)f2bf(v0.z); af[3] = (short)f2bf(v0.w);
      af[4] = (short)f2bf(v1.x); af[5] = (short)f2bf(v1.y);
      af[6] = (short)f2bf(v1.z); af[7] = (short)f2bf(v1.w);
#pragma unroll
      for (int cf = 0; cf < 4; ++cf)
        acc[rf][cf] = __builtin_amdgcn_mfma_f32_16x16x32_bf16(af, bfr[cf], acc[rf][cf], 0, 0, 0);
    }
    __syncthreads();
  }

  float bvv[4];
#pragma unroll
  for (int cf = 0; cf < 4; ++cf)
    bvv[cf] = bias[w * 64 + cf * 16 + (lane & 15)] * bscale;

  if (z < 2) {
    unsigned short* o = (z == 0) ? qbf : kbf;
#pragma unroll
    for (int rf = 0; rf < 4; ++rf)
#pragma unroll
      for (int cf = 0; cf < 4; ++cf)
#pragma unroll
        for (int r = 0; r < 4; ++r) {
          int m = m0 + rf * 16 + (lane >> 4) * 4 + r;
          int h = w * 64 + cf * 16 + (lane & 15);
          o[(size_t)m * DH + h] = f2bf(acc[rf][cf][r] + bvv[cf]);
        }
  } else {
    int bb = m0 >> 12;
    int sl = m0 & 4095;
#pragma unroll
    for (int rf = 0; rf < 4; ++rf)
#pragma unroll
      for (int cf = 0; cf < 4; ++cf) {
        int s = sl + rf * 16 + (lane >> 4) * 4;
        int h = w * 64 + cf * 16 + (lane & 15);
        ushort4v o;
        o.x = f2bf(acc[rf][cf][0] + bvv[cf]);
        o.y = f2bf(acc[rf][cf][1] + bvv[cf]);
        o.z = f2bf(acc[rf][cf][2] + bvv[cf]);
        o.w = f2bf(acc[rf][cf][3] + bvv[cf]);
        *(ushort4v*)(vtbf + ((size_t)(bb * DH + h)) * S_LEN + s) = o;
      }
  }
}

// ---------------------------------------------------------------------------
// Kernel 3: fused masked attention — r9 discipline, KVB=128 (NT=32, half the
// iterations, double the per-iteration work). K staged via gl2lds dbuf
// (2x64KB); V DIRECT global->regs (r10-proven L2-hit pattern, consumed only
// after barrier1 so latency hides under QK+softmax); P single 16KB with the
// r9 field-swap involution extended to 128 kv (4 chunks of 32 kv per qgroup).
//   QK role:  kvs = w&3 (32-kv slice), qh = w>>2 (32 q rows)
//   PV role:  qs = w>>2 (32 q rows),  hs = w&3 (64 h cols)
// Softmax without max (scores bounded; exp(0)=1 = reference fill-0).
// LDS: K 2x64KB | P 16KB | l 1KB = 148480 B, 1 block/CU, 8 waves.
// ---------------------------------------------------------------------------
__global__ void __launch_bounds__(512, 2)
attn_kernel(const unsigned short* __restrict__ qbf,
            const unsigned short* __restrict__ kbf,
            const unsigned short* __restrict__ vtbf,
            const ull* __restrict__ mbits,
            float* __restrict__ out) {
  const int tid  = threadIdx.x;
  const int lane = tid & 63;
  const int w    = tid >> 6;          // 0..7
  const int j    = lane & 15;
  const int g    = lane >> 4;
  const int lane16 = lane * 16;

  const int kvs = w & 3;              // QK role: 32-kv slice
  const int qh  = w >> 2;
  const int qs  = w >> 2;             // PV role
  const int hs  = w & 3;

  // XCD-aware decode (blocks on one XCD share a batch)
  const int bx = blockIdx.x;
  const int x  = bx & 7;
  const int b  = x >> 1;
  const int qt = (bx >> 3) * 2 + (x & 1);
  const int m0 = qt * 64;

  __shared__ char sbuf[148480];
  // K: buf*65536 [0,131072) ; P: 131072 [16KB) ; l: 147456 [64][4] f32
  float* lbuf = (float*)(sbuf + 147456);

  // ---- Q fragments: rows qh*32 + qf*16 + j, k-chunks kc (h = kc*32 + g*8)
  short8 qreg[2][8];
#pragma unroll
  for (int qf = 0; qf < 2; ++qf) {
    const unsigned short* qrow =
        qbf + ((size_t)(b * S_LEN + m0 + qh * 32 + qf * 16 + j)) * DH + g * 8;
#pragma unroll
    for (int kc = 0; kc < 8; ++kc) qreg[qf][kc] = *(const short8*)(qrow + kc * 32);
  }

  f32x4 zero = {0.f, 0.f, 0.f, 0.f};
  f32x4 acc[2][4];
#pragma unroll
  for (int a = 0; a < 2; ++a)
#pragma unroll
    for (int hf = 0; hf < 4; ++hf) acc[a][hf] = zero;
  float lrow[2][4] = {{0.f, 0.f, 0.f, 0.f}, {0.f, 0.f, 0.f, 0.f}};
  short8 vreg[4][4];                   // V(t) frags [hf][kvc]

  // mask bits: q = m0 + qh*32 + g*4 + qf*16 + r ; word 2t + (kvs>>1) ;
  // packed 2-bit extract: bit0 = kvf0, bit16 = kvf1
  const ull* mwb = mbits + ((size_t)(b * S_LEN + m0 + qh * 32 + g * 4)) * 64;
  const int mshift = (kvs & 1) * 32 + j;

  // ---- K staging: 64 chunks of 1KB (ks = chunk>>3 = 16-kv group, kc = d).
  // Wave w stages ks = w, all 8 d-chunks; wave-uniform LDS dst.
  auto stageK = [&](int t1, int bufbase) {
    const char* src = (const char*)kbf +
        ((size_t)(b * S_LEN + t1 * 128 + w * 16 + j)) * 512 + g * 16;
    char* dst = sbuf + bufbase + w * 8192;
#pragma unroll
    for (int i = 0; i < 8; ++i)
      gl2lds16(src + i * 64, dst + i * 1024);
  };

  // V-frag direct base (PV role): row = b*DH + hs*64 + hf*16 + j
  const unsigned short* vbase =
      vtbf + ((size_t)(b * DH + hs * 64 + j)) * S_LEN + g * 8;

  // P region: qgroup(qh,qf)*4096 + kvchunk*1024 + (kvf*2 + (j>>3))*256
  //           + (r*4+g)*16 + (j&7)*2   (involution row' = r*4+g)
  const int pwb = (qh * 2) * 4096 + kvs * 1024 + (j >> 3) * 256 + (j & 7) * 2;

  // prologue
  stageK(0, 0);
  __syncthreads();

  const int NT = S_LEN / 128;   // 32
  for (int t = 0; t < NT; ++t) {
    const int bufb = (t & 1) * 65536;

    // ---- mask words for tile t (oldest in FIFO; consumed at softmax)
    int mplex[8];
#pragma unroll
    for (int qf = 0; qf < 2; ++qf)
#pragma unroll
      for (int r = 0; r < 4; ++r)
        mplex[qf * 4 + r] =
            (int)(mwb[(qf * 16 + r) * 64 + 2 * t + (kvs >> 1)] >> mshift);

    // ---- V(t) -> regs (consumed after barrier1; latency hides under QK)
    {
      const unsigned short* vt = vbase + t * 128;
#pragma unroll
      for (int hf = 0; hf < 4; ++hf)
#pragma unroll
        for (int kvc = 0; kvc < 4; ++kvc)
          vreg[hf][kvc] = *(const short8*)(vt + (size_t)(hf * 16) * S_LEN + kvc * 32);
    }

    if (t + 1 < NT) stageK(t + 1, bufb ^ 65536);  // drains at barrier1

    // ---- QK(t): 32 MFMA over the wave's 32-kv slice
    const char* kb = sbuf + bufb + kvs * 16384;
    f32x4 sc[2][2];                     // [qf][kvf]
    sc[0][0] = zero; sc[0][1] = zero; sc[1][0] = zero; sc[1][1] = zero;
    __builtin_amdgcn_s_setprio(1);
#pragma unroll
    for (int kc = 0; kc < 8; ++kc) {
      short8 k0 = *(const short8*)(kb + kc * 1024 + lane16);
      short8 k1 = *(const short8*)(kb + (8 + kc) * 1024 + lane16);
      sc[0][0] = __builtin_amdgcn_mfma_f32_16x16x32_bf16(qreg[0][kc], k0, sc[0][0], 0, 0, 0);
      sc[1][0] = __builtin_amdgcn_mfma_f32_16x16x32_bf16(qreg[1][kc], k0, sc[1][0], 0, 0, 0);
      sc[0][1] = __builtin_amdgcn_mfma_f32_16x16x32_bf16(qreg[0][kc], k1, sc[0][1], 0, 0, 0);
      sc[1][1] = __builtin_amdgcn_mfma_f32_16x16x32_bf16(qreg[1][kc], k1, sc[1][1], 0, 0, 0);
    }
    __builtin_amdgcn_s_setprio(0);

    // ---- softmax (no max): p = maskbit ? exp(s) : 1 ; write P (bf16)
#pragma unroll
    for (int qf = 0; qf < 2; ++qf) {
      int cb = pwb + qf * 4096;
#pragma unroll
      for (int r = 0; r < 4; ++r) {
        int m = mplex[qf * 4 + r];
        float sv0 = (m & 1)       ? sc[qf][0][r] : 0.0f;
        float sv1 = (m & 0x10000) ? sc[qf][1][r] : 0.0f;
        float e0 = __expf(sv0);
        float e1 = __expf(sv1);
        lrow[qf][r] += e0 + e1;
        *(unsigned short*)(sbuf + 131072 + cb + (r * 4 + g) * 16)       = f2bf(e0);
        *(unsigned short*)(sbuf + 131072 + cb + 512 + (r * 4 + g) * 16) = f2bf(e1);
      }
    }
    __syncthreads();                   // barrier1: P ready; K(t+1) staged

    // ---- PV(t): P from LDS, V from regs; per-kc2 to cap VGPR
    const char* pbase = sbuf + 131072 + (qs * 2) * 4096;
    __builtin_amdgcn_s_setprio(1);
#pragma unroll
    for (int kc2 = 0; kc2 < 4; ++kc2) {
      short8 pf0 = *(const short8*)(pbase + kc2 * 1024 + lane16);
      short8 pf1 = *(const short8*)(pbase + 4096 + kc2 * 1024 + lane16);
#pragma unroll
      for (int hf = 0; hf < 4; ++hf) {
        acc[0][hf] = __builtin_amdgcn_mfma_f32_16x16x32_bf16(pf0, vreg[hf][kc2], acc[0][hf], 0, 0, 0);
        acc[1][hf] = __builtin_amdgcn_mfma_f32_16x16x32_bf16(pf1, vreg[hf][kc2], acc[1][hf], 0, 0, 0);
      }
    }
    __builtin_amdgcn_s_setprio(0);

    __syncthreads();                   // barrier2: P consumed
  }

  // ---- epilogue (r9-verbatim): reduce l over 16 j-lanes, exchange slices
#pragma unroll
  for (int qf = 0; qf < 2; ++qf)
#pragma unroll
    for (int r = 0; r < 4; ++r) {
#pragma unroll
      for (int off = 1; off < 16; off <<= 1)
        lrow[qf][r] += __shfl_xor(lrow[qf][r], off, 64);
    }
  if (j == 0) {
#pragma unroll
    for (int qf = 0; qf < 2; ++qf)
#pragma unroll
      for (int r = 0; r < 4; ++r)
        lbuf[(qh * 32 + qf * 16 + g * 4 + r) * 4 + kvs] = lrow[qf][r];
  }
  __syncthreads();

#pragma unroll
  for (int qf2 = 0; qf2 < 2; ++qf2)
#pragma unroll
    for (int rr = 0; rr < 4; ++rr) {
      int qb = qs * 32 + qf2 * 16 + rr * 4 + g;   // physical q (fields swapped back)
      f32x4 lv = *(const f32x4*)&lbuf[qb * 4];
      float linv = 1.0f / (lv[0] + lv[1] + lv[2] + lv[3]);
      float* orow = out + ((size_t)(b * S_LEN + m0 + qb)) * DH + hs * 64 + j;
#pragma unroll
      for (int hf = 0; hf < 4; ++hf)
        orow[hf * 16] = acc[qf2][hf][rr] * linv;
    }
}

// ---------------------------------------------------------------------------
extern "C" void kernel_launch(void* const* d_in, const int* in_sizes, int n_in,
                              void* d_out, int out_size, void* d_ws, size_t ws_size,
                              hipStream_t stream) {
  const float* xq = (const float*)d_in[0];
  const float* xk = (const float*)d_in[1];
  const float* xv = (const float*)d_in[2];
  const int* mask = (const int*)d_in[3];
  const float* wq = (const float*)d_in[4];
  const float* bq = (const float*)d_in[5];
  const float* wk = (const float*)d_in[6];
  const float* bk = (const float*)d_in[7];
  const float* wv = (const float*)d_in[8];
  const float* bv = (const float*)d_in[9];
  float* out = (float*)d_out;

  char* ws = (char*)d_ws;
  unsigned short* wbf  = (unsigned short*)(ws);                    // 1.5 MB
  unsigned short* qbf  = (unsigned short*)(ws + (2ull  << 20));    // 8 MB
  unsigned short* kbf  = (unsigned short*)(ws + (10ull << 20));    // 8 MB
  unsigned short* vtbf = (unsigned short*)(ws + (18ull << 20));    // 8 MB
  ull*            mbit = (ull*)           (ws + (26ull << 20));    // 8 MB

  hipLaunchKernelGGL(mcomp_kernel, dim3(1024), dim3(256), 0, stream, mask, mbit);
  hipLaunchKernelGGL(wcvt_kernel, dim3(768), dim3(256), 0, stream, wq, wk, wv, wbf);
  hipLaunchKernelGGL(proj_kernel, dim3(256, 1, 3), dim3(256), 0, stream,
                     xq, xk, xv, wbf, bq, bk, bv, qbf, kbf, vtbf);
  hipLaunchKernelGGL(attn_kernel, dim3(256), dim3(512), 0, stream,
                     qbf, kbf, vtbf, mbit, out);
}

// Round 12
// 239.074 us; speedup vs baseline: 1.8636x; 1.5933x over previous
//
#include <hip/hip_runtime.h>
#include <cstdint>
#include <cstddef>

#define S_LEN 4096
#define DVEC  1024
#define DH    256

typedef __attribute__((ext_vector_type(8))) short short8;
typedef __attribute__((ext_vector_type(4))) float f32x4;
typedef __attribute__((ext_vector_type(4))) unsigned short ushort4v;

__device__ __forceinline__ unsigned short f2bf(float f) {
  unsigned u = __builtin_bit_cast(unsigned, f);
  u += 0x7FFFu + ((u >> 16) & 1u);          // round-to-nearest-even
  return (unsigned short)(u >> 16);
}

__device__ __forceinline__ void gl2lds16(const void* g, void* lds) {
  __builtin_amdgcn_global_load_lds(
      (const __attribute__((address_space(1))) unsigned int*)g,
      (__attribute__((address_space(3))) unsigned int*)lds, 16, 0, 0);
}

// Counted-vmcnt barrier (T4): waits only until <=N vmem ops remain in this
// wave's FIFO, so the NEXT tile's prefetch stays in flight across the
// barrier. N=12 = ops younger than the load the barrier must guarantee
// (4 gl2lds stage + 8 mask dwords issued after it). "memory" clobbers pin
// loads/stores within their phase at IR level.
__device__ __forceinline__ void wait_bar_12() {
  asm volatile("s_waitcnt vmcnt(12) lgkmcnt(0)" ::: "memory");
  __builtin_amdgcn_s_barrier();
  asm volatile("" ::: "memory");
}
__device__ __forceinline__ void wait_bar_0() {
  asm volatile("s_waitcnt vmcnt(0) lgkmcnt(0)" ::: "memory");
  __builtin_amdgcn_s_barrier();
  asm volatile("" ::: "memory");
}

// ---------------------------------------------------------------------------
// Kernel 1: weights f32 -> bf16 (wq pre-scaled by 1/sqrt(DH)=1/16).
// ---------------------------------------------------------------------------
__global__ void wcvt_kernel(const float* __restrict__ wq,
                            const float* __restrict__ wk,
                            const float* __restrict__ wv,
                            unsigned short* __restrict__ wbf) {
  int t   = blockIdx.x * 256 + threadIdx.x;
  int idx = t * 4;
  int m   = idx >> 18;
  int off = idx & 262143;
  const float* src = (m == 0) ? wq : (m == 1) ? wk : wv;
  float scale = (m == 0) ? 0.0625f : 1.0f;
  f32x4 v = *(const f32x4*)(src + off);
  ushort4v o;
  o.x = f2bf(v.x * scale);
  o.y = f2bf(v.y * scale);
  o.z = f2bf(v.z * scale);
  o.w = f2bf(v.w * scale);
  *(ushort4v*)(wbf + idx) = o;
}

// ---------------------------------------------------------------------------
// Kernel 2: projection GEMM (unchanged). C = x * W^T + b -> bf16; z==2 -> V^T.
// ---------------------------------------------------------------------------
__global__ void proj_kernel(const float* __restrict__ xq,
                            const float* __restrict__ xk,
                            const float* __restrict__ xv,
                            const unsigned short* __restrict__ wbf,
                            const float* __restrict__ bq,
                            const float* __restrict__ bk,
                            const float* __restrict__ bv,
                            unsigned short* __restrict__ qbf,
                            unsigned short* __restrict__ kbf,
                            unsigned short* __restrict__ vtbf) {
  const int tid  = threadIdx.x;
  const int lane = tid & 63;
  const int w    = tid >> 6;
  const int z    = blockIdx.z;
  const int m0   = blockIdx.x * 64;

  const float* x = (z == 0) ? xq : (z == 1) ? xk : xv;
  const unsigned short* wz = wbf + (size_t)z * (DH * DVEC);
  const float* bias = (z == 0) ? bq : (z == 1) ? bk : bv;
  const float bscale = (z == 0) ? 0.0625f : 1.0f;

  __shared__ float At[2][64 * 32];

  f32x4 zero = {0.f, 0.f, 0.f, 0.f};
  f32x4 acc[4][4];
#pragma unroll
  for (int i = 0; i < 4; ++i)
#pragma unroll
    for (int j = 0; j < 4; ++j) acc[i][j] = zero;

  auto stage = [&](int kt, int buf) {
    char* dstb = (char*)&At[buf][0] + w * 2048;
#pragma unroll
    for (int i = 0; i < 2; ++i) {
      int lin  = w * 2048 + i * 1024 + lane * 16;
      int row  = lin >> 7;
      int scol = (lin ^ ((row & 7) << 4)) & 127;
      gl2lds16((const char*)x + ((size_t)(m0 + row) * DVEC + kt * 32) * 4 + scol,
               dstb + i * 1024);
    }
  };

  stage(0, 0);
  __syncthreads();

  for (int kt = 0; kt < 32; ++kt) {
    const int buf = kt & 1;
    if (kt + 1 < 32) stage(kt + 1, buf ^ 1);

    short8 bfr[4];
#pragma unroll
    for (int cf = 0; cf < 4; ++cf) {
      int h = w * 64 + cf * 16 + (lane & 15);
      int d = kt * 32 + (lane >> 4) * 8;
      bfr[cf] = *(const short8*)(wz + (size_t)h * DVEC + d);
    }
    const char* ab = (const char*)&At[buf][0];
#pragma unroll
    for (int rf = 0; rf < 4; ++rf) {
      int row = rf * 16 + (lane & 15);
      int c0  = row * 128 + (lane >> 4) * 32;
      int sw  = (row & 7) << 4;
      f32x4 v0 = *(const f32x4*)(ab + (c0 ^ sw));
      f32x4 v1 = *(const f32x4*)(ab + ((c0 + 16) ^ sw));
      short8 af;
      af[0] = (short)f2bf(v0.x); af[1] = (short)f2bf(v0.y);
      af[2] = (short)f2bf(v0.z); af[3] = (short)f2bf(v0.w);
      af[4] = (short)f2bf(v1.x); af[5] = (short)f2bf(v1.y);
      af[6] = (short)f2bf(v1.z); af[7] = (short)f2bf(v1.w);
#pragma unroll
      for (int cf = 0; cf < 4; ++cf)
        acc[rf][cf] = __builtin_amdgcn_mfma_f32_16x16x32_bf16(af, bfr[cf], acc[rf][cf], 0, 0, 0);
    }
    __syncthreads();
  }

  float bvv[4];
#pragma unroll
  for (int cf = 0; cf < 4; ++cf)
    bvv[cf] = bias[w * 64 + cf * 16 + (lane & 15)] * bscale;

  if (z < 2) {
    unsigned short* o = (z == 0) ? qbf : kbf;
#pragma unroll
    for (int rf = 0; rf < 4; ++rf)
#pragma unroll
      for (int cf = 0; cf < 4; ++cf)
#pragma unroll
        for (int r = 0; r < 4; ++r) {
          int m = m0 + rf * 16 + (lane >> 4) * 4 + r;
          int h = w * 64 + cf * 16 + (lane & 15);
          o[(size_t)m * DH + h] = f2bf(acc[rf][cf][r] + bvv[cf]);
        }
  } else {
    int bb = m0 >> 12;
    int sl = m0 & 4095;
#pragma unroll
    for (int rf = 0; rf < 4; ++rf)
#pragma unroll
      for (int cf = 0; cf < 4; ++cf) {
        int s = sl + rf * 16 + (lane >> 4) * 4;
        int h = w * 64 + cf * 16 + (lane & 15);
        ushort4v o;
        o.x = f2bf(acc[rf][cf][0] + bvv[cf]);
        o.y = f2bf(acc[rf][cf][1] + bvv[cf]);
        o.z = f2bf(acc[rf][cf][2] + bvv[cf]);
        o.w = f2bf(acc[rf][cf][3] + bvv[cf]);
        *(ushort4v*)(vtbf + ((size_t)(bb * DH + h)) * S_LEN + s) = o;
      }
  }
}

// ---------------------------------------------------------------------------
// Kernel 3: fused masked attention — ROUND-4 STRUCTURE VERBATIM (verified),
// with exactly ONE change: the two __syncthreads() in the K/V loop are
// replaced by counted-vmcnt barriers (T4) so the next tile's gl2lds prefetch
// is NOT drained at each barrier.
// Per-iteration vmem program order: stageK(t+1) 4 gl2lds -> mask 8 dwords ->
// [QK, softmax, P] -> BAR1(vmcnt 12: drains stageV(t), keeps newer 12) ->
// stageV(t+1) 4 gl2lds -> [PV] -> BAR2(vmcnt 12: drains stageK(t+1)).
// Block = 64 q rows, KVB = 64, 8 waves.
//   QK role:  wave w -> (kvs = w&3: 16-kv slice, qh = w>>2: 32 q rows)
//   PV role:  wave w -> (qs = w>>2: 32 q rows,  hs = w&3: 64 h cols)
// Softmax without max (scores bounded; exp(0)=1 matches reference fill-0).
// LDS: K 2x32KB | V 2x32KB | P 8KB | l 1KB = 140288 bytes.
// ---------------------------------------------------------------------------
__global__ void __launch_bounds__(512, 2)
attn_kernel(const unsigned short* __restrict__ qbf,
            const unsigned short* __restrict__ kbf,
            const unsigned short* __restrict__ vtbf,
            const int* __restrict__ mask,
            float* __restrict__ out) {
  const int tid  = threadIdx.x;
  const int lane = tid & 63;
  const int w    = tid >> 6;          // 0..7
  const int j    = lane & 15;
  const int g    = lane >> 4;

  const int kvs = w & 3;              // QK role
  const int qh  = w >> 2;
  const int qs  = w >> 2;             // PV role
  const int hs  = w & 3;

  // XCD-aware decode (blocks on one XCD share a batch -> K/V L2-resident)
  const int bx = blockIdx.x;
  const int x  = bx & 7;
  const int b  = x >> 1;
  const int qt = (bx >> 3) * 2 + (x & 1);
  const int m0 = qt * 64;

  __shared__ char sbuf[140288];
  // K: buf*32768 ; V: 65536 + buf*32768 ; P: 131072 ; l: 139264

  // ---- Q fragments: rows qh*32 + qf*16 + j, k-chunks kc (h = kc*32 + g*8)
  short8 qreg[2][8];
#pragma unroll
  for (int qf = 0; qf < 2; ++qf) {
    const unsigned short* qrow =
        qbf + ((size_t)(b * S_LEN + m0 + qh * 32 + qf * 16 + j)) * DH + g * 8;
#pragma unroll
    for (int kc = 0; kc < 8; ++kc) qreg[qf][kc] = *(const short8*)(qrow + kc * 32);
  }

  f32x4 zero = {0.f, 0.f, 0.f, 0.f};
  f32x4 acc[2][4];
#pragma unroll
  for (int a = 0; a < 2; ++a)
#pragma unroll
    for (int hf = 0; hf < 4; ++hf) acc[a][hf] = zero;
  float lrow[2][4] = {{0.f, 0.f, 0.f, 0.f}, {0.f, 0.f, 0.f, 0.f}};

  // raw mask (element read exactly once grid-wide; compression is net loss)
  const int* mb = mask + ((size_t)(b * S_LEN + m0 + qh * 32 + g * 4)) * S_LEN + kvs * 16 + j;

  // ---- staging: 32 chunks of 1KB each, 4 per wave, wave-uniform LDS dst
  auto stageK = [&](int t, int buf) {
    const char* src = (const char*)kbf + ((size_t)(b * S_LEN) + t * 64) * 512;
    char* dst = sbuf + buf * 32768 + w * 4096;
#pragma unroll
    for (int i = 0; i < 4; ++i) {
      int rid = w * 4 + i;            // (ks = rid>>3, kc = rid&7)
      int ks  = rid >> 3;
      int kc  = rid & 7;
      gl2lds16(src + (size_t)(ks * 16 + j) * 512 + kc * 64 + g * 16, dst + i * 1024);
    }
  };
  auto stageV = [&](int t, int buf) {
    char* dst = sbuf + 65536 + buf * 32768 + w * 4096;
#pragma unroll
    for (int i = 0; i < 4; ++i) {
      int rid = w * 4 + i;            // (h16 = rid>>1, kc2 = rid&1)
      int h16 = rid >> 1;
      int kc2 = rid & 1;
      const char* src = (const char*)vtbf +
          (((size_t)(b * DH + h16 * 16 + j)) * S_LEN + t * 64 + kc2 * 32 + g * 8) * 2;
      gl2lds16(src, dst + i * 1024);
    }
  };

  int mcur[8], mnext[8];
#pragma unroll
  for (int qf = 0; qf < 2; ++qf)
#pragma unroll
    for (int r = 0; r < 4; ++r) mcur[qf * 4 + r] = mb[(qf * 16 + r) * S_LEN];
  stageK(0, 0);
  stageV(0, 0);
  __syncthreads();

  // P-write base: chunk (qi*2 + kvs>>1), slot fields: g2 = (kvs&1)*2 + (j>>3),
  // row' = r*4+g (involution), byte low = (j&7)*2
  const int pwbase = 131072 + (kvs >> 1) * 1024 + ((kvs & 1) * 2 + (j >> 3)) * 256 + (j & 7) * 2;

  const int NT = S_LEN / 64;   // 64
  for (int t = 0; t < NT; ++t) {
    const int buf = t & 1;
    if (t + 1 < NT) {
      stageK(t + 1, buf ^ 1);          // 4 gl2lds, stays in flight past BAR1
#pragma unroll
      for (int qf = 0; qf < 2; ++qf)
#pragma unroll
        for (int r = 0; r < 4; ++r)
          mnext[qf * 4 + r] = mb[(qf * 16 + r) * S_LEN + (t + 1) * 64];
    }

    // ---- QK: sc = Q(32q) x K-slice(16kv), 4 interleaved MFMA chains
    const char* kb = sbuf + buf * 32768 + kvs * 8192;
    f32x4 s0[2], s1[2];
    s0[0] = zero; s0[1] = zero; s1[0] = zero; s1[1] = zero;
    __builtin_amdgcn_s_setprio(1);
#pragma unroll
    for (int kc = 0; kc < 8; kc += 2) {
      short8 k0 = *(const short8*)(kb + kc * 1024 + lane * 16);
      short8 k1 = *(const short8*)(kb + (kc + 1) * 1024 + lane * 16);
      s0[0] = __builtin_amdgcn_mfma_f32_16x16x32_bf16(qreg[0][kc], k0, s0[0], 0, 0, 0);
      s0[1] = __builtin_amdgcn_mfma_f32_16x16x32_bf16(qreg[1][kc], k0, s0[1], 0, 0, 0);
      s1[0] = __builtin_amdgcn_mfma_f32_16x16x32_bf16(qreg[0][kc + 1], k1, s1[0], 0, 0, 0);
      s1[1] = __builtin_amdgcn_mfma_f32_16x16x32_bf16(qreg[1][kc + 1], k1, s1[1], 0, 0, 0);
    }
    __builtin_amdgcn_s_setprio(0);

    // ---- softmax (no max): p = mask ? exp(s) : 1 ; write P (bf16)
#pragma unroll
    for (int qf = 0; qf < 2; ++qf) {
      int cb = pwbase + (qh * 2 + qf) * 2048;
#pragma unroll
      for (int r = 0; r < 4; ++r) {
        float sv = s0[qf][r] + s1[qf][r];
        sv = mcur[qf * 4 + r] ? sv : 0.0f;
        float e = __expf(sv);
        lrow[qf][r] += e;
        *(unsigned short*)(sbuf + cb + (r * 4 + g) * 16) = f2bf(e);
      }
    }

    // BAR1: drains stageV(t) (12 younger ops stay in flight); P visible.
    if (t + 1 < NT) wait_bar_12(); else wait_bar_0();

    if (t + 1 < NT) stageV(t + 1, buf ^ 1);  // 4 gl2lds, in flight past BAR2

    // ---- PV: O(32q x 64h) += P(32q x 64kv) x V(64kv x 64h)
    const char* vb = sbuf + 65536 + buf * 32768 + hs * 8192;
    short8 pf[2][2];
#pragma unroll
    for (int qf2 = 0; qf2 < 2; ++qf2)
#pragma unroll
      for (int kc2 = 0; kc2 < 2; ++kc2)
        pf[qf2][kc2] = *(const short8*)(sbuf + 131072 + ((qs * 2 + qf2) * 2 + kc2) * 1024 + lane * 16);
    __builtin_amdgcn_s_setprio(1);
#pragma unroll
    for (int hf = 0; hf < 4; ++hf) {
      short8 v0 = *(const short8*)(vb + (hf * 2 + 0) * 1024 + lane * 16);
      short8 v1 = *(const short8*)(vb + (hf * 2 + 1) * 1024 + lane * 16);
      acc[0][hf] = __builtin_amdgcn_mfma_f32_16x16x32_bf16(pf[0][0], v0, acc[0][hf], 0, 0, 0);
      acc[1][hf] = __builtin_amdgcn_mfma_f32_16x16x32_bf16(pf[1][0], v0, acc[1][hf], 0, 0, 0);
      acc[0][hf] = __builtin_amdgcn_mfma_f32_16x16x32_bf16(pf[0][1], v1, acc[0][hf], 0, 0, 0);
      acc[1][hf] = __builtin_amdgcn_mfma_f32_16x16x32_bf16(pf[1][1], v1, acc[1][hf], 0, 0, 0);
    }
    __builtin_amdgcn_s_setprio(0);

#pragma unroll
    for (int i = 0; i < 8; ++i) mcur[i] = mnext[i];

    // BAR2: drains stageK(t+1) (12 younger ops stay in flight); P consumed.
    if (t + 1 < NT) wait_bar_12(); else wait_bar_0();
  }

  // ---- epilogue: reduce l over 16 j-lanes, exchange 4 kv-slices via LDS
#pragma unroll
  for (int qf = 0; qf < 2; ++qf)
#pragma unroll
    for (int r = 0; r < 4; ++r) {
#pragma unroll
      for (int off = 1; off < 16; off <<= 1)
        lrow[qf][r] += __shfl_xor(lrow[qf][r], off, 64);
    }
  float* lbuf = (float*)(sbuf + 139264);   // [64][4]
  if (j == 0) {
#pragma unroll
    for (int qf = 0; qf < 2; ++qf)
#pragma unroll
      for (int r = 0; r < 4; ++r)
        lbuf[(qh * 32 + qf * 16 + g * 4 + r) * 4 + kvs] = lrow[qf][r];
  }
  __syncthreads();

#pragma unroll
  for (int qf2 = 0; qf2 < 2; ++qf2)
#pragma unroll
    for (int rr = 0; rr < 4; ++rr) {
      int qb = qs * 32 + qf2 * 16 + rr * 4 + g;   // physical q (fields swapped back)
      f32x4 lv = *(const f32x4*)&lbuf[qb * 4];
      float linv = 1.0f / (lv[0] + lv[1] + lv[2] + lv[3]);
      float* orow = out + ((size_t)(b * S_LEN + m0 + qb)) * DH + hs * 64 + j;
#pragma unroll
      for (int hf = 0; hf < 4; ++hf)
        orow[hf * 16] = acc[qf2][hf][rr] * linv;
    }
}

// ---------------------------------------------------------------------------
extern "C" void kernel_launch(void* const* d_in, const int* in_sizes, int n_in,
                              void* d_out, int out_size, void* d_ws, size_t ws_size,
                              hipStream_t stream) {
  const float* xq = (const float*)d_in[0];
  const float* xk = (const float*)d_in[1];
  const float* xv = (const float*)d_in[2];
  const int* mask = (const int*)d_in[3];
  const float* wq = (const float*)d_in[4];
  const float* bq = (const float*)d_in[5];
  const float* wk = (const float*)d_in[6];
  const float* bk = (const float*)d_in[7];
  const float* wv = (const float*)d_in[8];
  const float* bv = (const float*)d_in[9];
  float* out = (float*)d_out;

  char* ws = (char*)d_ws;
  unsigned short* wbf  = (unsigned short*)(ws);                    // 1.5 MB
  unsigned short* qbf  = (unsigned short*)(ws + (2ull  << 20));    // 8 MB
  unsigned short* kbf  = (unsigned short*)(ws + (10ull << 20));    // 8 MB
  unsigned short* vtbf = (unsigned short*)(ws + (18ull << 20));    // 8 MB

  hipLaunchKernelGGL(wcvt_kernel, dim3(768), dim3(256), 0, stream, wq, wk, wv, wbf);
  hipLaunchKernelGGL(proj_kernel, dim3(256, 1, 3), dim3(256), 0, stream,
                     xq, xk, xv, wbf, bq, bk, bv, qbf, kbf, vtbf);
  hipLaunchKernelGGL(attn_kernel, dim3(256), dim3(512), 0, stream,
                     qbf, kbf, vtbf, mask, out);
}